// Round 5
// baseline (224.669 us; speedup 1.0000x reference)
//
#include <hip/hip_runtime.h>
#include <hip/hip_bf16.h>
#include <stdint.h>

#define B_ 4
#define M_ 1024
#define N_ 2048
#define D_ 1024
#define H_ 16
#define DH_ 64

typedef __bf16 bf16_t;
typedef __attribute__((ext_vector_type(8))) __bf16 bf16x8;
typedef __attribute__((ext_vector_type(4))) float f32x4;

static __device__ __forceinline__ float silu_f(float x) {
  return x / (1.0f + __expf(-x));
}

// ---- K1: K' = L2norm(silu(kv heads)) -> kp[bh][n][d]. Fully coalesced reads.
__global__ __launch_bounds__(256) void prep_k_kernel(
    const float* __restrict__ kv, bf16_t* __restrict__ kp) {
  const int w = threadIdx.x >> 6, lane = threadIdx.x & 63;
  const int row = blockIdx.x * 4 + w;
  const int b = row >> 11, n = row & (N_ - 1);
  const float* src = kv + (size_t)row * D_;
  #pragma unroll
  for (int i = 0; i < 4; ++i) {
    float4 v = *(const float4*)(src + i * 256 + lane * 4);
    float s0 = silu_f(v.x), s1 = silu_f(v.y), s2 = silu_f(v.z), s3 = silu_f(v.w);
    float ss = s0 * s0 + s1 * s1 + s2 * s2 + s3 * s3;
    ss += __shfl_xor(ss, 1); ss += __shfl_xor(ss, 2);
    ss += __shfl_xor(ss, 4); ss += __shfl_xor(ss, 8);
    const float inv = 1.0f / fmaxf(sqrtf(ss), 1e-6f);
    const int h = i * 4 + (lane >> 4);
    union { bf16_t b4[4]; uint2 u; } pk;
    pk.b4[0] = (bf16_t)(s0 * inv); pk.b4[1] = (bf16_t)(s1 * inv);
    pk.b4[2] = (bf16_t)(s2 * inv); pk.b4[3] = (bf16_t)(s3 * inv);
    *(uint2*)(kp + ((size_t)(b * H_ + h) * N_ + n) * DH_ + (lane & 15) * 4) = pk.u;
  }
}

// ---- K2: Vt = kv heads transposed -> vt[bh][d][n] (bf16), via LDS tile.
__global__ __launch_bounds__(256) void prep_v_kernel(
    const float* __restrict__ kv, bf16_t* __restrict__ vt) {
  __shared__ __align__(16) bf16_t Vt2[256][68];
  const int bx = blockIdx.x;
  const int h = bx & 15, nt = (bx >> 4) & 7, b = bx >> 7;
  const int n0 = nt * 256;
  const int tid = threadIdx.x;
  #pragma unroll
  for (int it = 0; it < 16; ++it) {
    const int r = it * 16 + (tid >> 4);
    const int c = (tid & 15) * 4;
    float4 v = *(const float4*)(kv + ((size_t)(b * N_ + n0 + r)) * D_ + h * DH_ + c);
    union { bf16_t b4[4]; uint2 u; } pk;
    pk.b4[0] = (bf16_t)v.x; pk.b4[1] = (bf16_t)v.y;
    pk.b4[2] = (bf16_t)v.z; pk.b4[3] = (bf16_t)v.w;
    *(uint2*)&Vt2[r][c] = pk.u;
  }
  __syncthreads();
  const size_t bh = (size_t)(b * H_ + h);
  #pragma unroll
  for (int pass = 0; pass < 4; ++pass) {
    const int d = pass * 16 + (tid >> 4);
    const int nst = (tid & 15) * 16;
    union { bf16_t bs[16]; uint4 u[2]; } pk;
    #pragma unroll
    for (int kk = 0; kk < 16; ++kk) pk.bs[kk] = Vt2[nst + kk][d];
    uint4* dst = (uint4*)(vt + (bh * DH_ + d) * N_ + n0 + nst);
    dst[0] = pk.u[0]; dst[1] = pk.u[1];
  }
}

// ---- K3: mask bits via ballot.
__global__ __launch_bounds__(256) void prep_mask_kernel(
    const int* __restrict__ kv_mask, unsigned long long* __restrict__ mb) {
  const int gw = (blockIdx.x * 256 + threadIdx.x) >> 6;
  const int lane = threadIdx.x & 63;
  unsigned long long m = __ballot(kv_mask[gw * 64 + lane] != 0);
  if (lane == 0) mb[gw] = m;
}

// ---- attn: LDS-free flash attention. S^T = K'Q'^T, O^T = V^T P^T.
//      MFMA operands loaded directly from global (L2-resident per XCD);
//      no __shared__, no __syncthreads -> compiler pipelines loads freely.
//      Block swizzle: bx = mtg*64 + bh so all m-blocks of a bh share an XCD.
__global__ __launch_bounds__(256, 2) void attn_kernel(
    const float* __restrict__ q, const bf16_t* __restrict__ kp,
    const bf16_t* __restrict__ vt, const unsigned long long* __restrict__ mb,
    float* __restrict__ out) {
  const int tid = threadIdx.x;
  const int w = tid >> 6, lane = tid & 63;
  const int l15 = lane & 15, quad = lane >> 4;
  const int bx = blockIdx.x;
  const int bh = bx & 63;
  const int mtg = bx >> 6;
  const int b = bh >> 4, h = bh & 15;
  const int m0 = mtg * 128 + w * 32;

  // Q B-frags direct from global: B[col m=l15][k d=quad*8+i], silu+L2norm.
  bf16x8 qa[2][2];
  #pragma unroll
  for (int mt = 0; mt < 2; ++mt) {
    const float* qrow =
        q + ((size_t)(b * M_ + m0 + mt * 16 + l15)) * D_ + h * DH_;
    float vals[16];
    float ss = 0.f;
    #pragma unroll
    for (int kc = 0; kc < 2; ++kc) {
      float4 a = *(const float4*)(qrow + kc * 32 + quad * 8);
      float4 c4 = *(const float4*)(qrow + kc * 32 + quad * 8 + 4);
      vals[kc * 8 + 0] = silu_f(a.x);  vals[kc * 8 + 1] = silu_f(a.y);
      vals[kc * 8 + 2] = silu_f(a.z);  vals[kc * 8 + 3] = silu_f(a.w);
      vals[kc * 8 + 4] = silu_f(c4.x); vals[kc * 8 + 5] = silu_f(c4.y);
      vals[kc * 8 + 6] = silu_f(c4.z); vals[kc * 8 + 7] = silu_f(c4.w);
    }
    #pragma unroll
    for (int i = 0; i < 16; ++i) ss += vals[i] * vals[i];
    ss += __shfl_xor(ss, 16); ss += __shfl_xor(ss, 32);  // reduce over quads
    const float inv = 1.0f / fmaxf(sqrtf(ss), 1e-6f);
    #pragma unroll
    for (int kc = 0; kc < 2; ++kc) {
      union { bf16_t b8[8]; bf16x8 v; } pq;
      #pragma unroll
      for (int i = 0; i < 8; ++i) pq.b8[i] = (bf16_t)(vals[kc * 8 + i] * inv);
      qa[mt][kc] = pq.v;
    }
  }

  f32x4 o[2][4];  // [mt][dt] : O^T, row d = dt*16+quad*4+r, col m = mt*16+l15
  float lsum[2] = {0.f, 0.f};
  #pragma unroll
  for (int mt = 0; mt < 2; ++mt)
    #pragma unroll
    for (int dt = 0; dt < 4; ++dt) o[mt][dt] = (f32x4){0.f, 0.f, 0.f, 0.f};

  const bf16_t* kpb = kp + (size_t)bh * N_ * DH_;
  const bf16_t* vtb = vt + (size_t)bh * DH_ * N_;
  const unsigned long long* mrow = mb + b * (N_ / 64);

  const int srcA = 32 * (quad & 1) + l15;  // lane with quad_s = 2*(quad&1)
  const int srcB = srcA + 16;
  const bool hi = quad >= 2;

  for (int t = 0; t < N_ / 64; ++t) {
    const int n0 = t * 64;
    // K' A-frags [j][kc]: row n=j*16+l15, k d=kc*32+quad*8  (16B/lane, 64B segs)
    // V^T A-frags [dt][kk]: row d=dt*16+l15, k n=n0+kk*32+quad*8
    bf16x8 kf[4][2], vf[4][2];
    #pragma unroll
    for (int j = 0; j < 4; ++j)
      #pragma unroll
      for (int kc = 0; kc < 2; ++kc) {
        kf[j][kc] = *(const bf16x8*)(kpb + (size_t)(n0 + j * 16 + l15) * DH_ +
                                     kc * 32 + quad * 8);
        vf[j][kc] = *(const bf16x8*)(vtb + (size_t)(j * 16 + l15) * N_ + n0 +
                                     kc * 32 + quad * 8);
      }
    const unsigned long long mk = mrow[t];

    // S^T = K' Q'^T : C row n=16j+quad*4+r, col m=l15
    f32x4 s[2][4];
    #pragma unroll
    for (int mt = 0; mt < 2; ++mt)
      #pragma unroll
      for (int j = 0; j < 4; ++j) s[mt][j] = (f32x4){0.f, 0.f, 0.f, 0.f};
    #pragma unroll
    for (int kc = 0; kc < 2; ++kc)
      #pragma unroll
      for (int j = 0; j < 4; ++j) {
        s[0][j] = __builtin_amdgcn_mfma_f32_16x16x32_bf16(kf[j][kc], qa[0][kc], s[0][j], 0, 0, 0);
        s[1][j] = __builtin_amdgcn_mfma_f32_16x16x32_bf16(kf[j][kc], qa[1][kc], s[1][j], 0, 0, 0);
      }

    // fixed-max softmax (unit vectors -> |s|<=1): p = exp(s/8 - 1/8), 0 if masked.
    uint32_t pkx[2][4][2];  // packed bf16 pairs (r=2rp, 2rp+1)
    #pragma unroll
    for (int mt = 0; mt < 2; ++mt)
      #pragma unroll
      for (int j = 0; j < 4; ++j)
        #pragma unroll
        for (int rp = 0; rp < 2; ++rp) {
          const int nb = 16 * j + quad * 4 + rp * 2;
          const float p0 = ((mk >> nb) & 1ull) ? 0.f
                           : __expf(s[mt][j][rp * 2] * 0.125f - 0.125f);
          const float p1 = ((mk >> (nb + 1)) & 1ull) ? 0.f
                           : __expf(s[mt][j][rp * 2 + 1] * 0.125f - 0.125f);
          lsum[mt] += p0 + p1;
          union { bf16_t b2[2]; uint32_t u; } t2;
          t2.b2[0] = (bf16_t)p0; t2.b2[1] = (bf16_t)p1;
          pkx[mt][j][rp] = t2.u;
        }

    // PV: O^T += V^T P^T. B-frag of P^T assembled by quad permutation:
    // target (kk,i): n_loc = 32kk + quad*8 + i  ==  16(2kk+hi) + quad_s*4 + (i&3)
    // with quad_s = 2*(quad&1) + (i>>2).  [verified algebraically]
    #pragma unroll
    for (int mt = 0; mt < 2; ++mt)
      #pragma unroll
      for (int kk = 0; kk < 2; ++kk) {
        const uint32_t a00 = __shfl(pkx[mt][2 * kk][0], srcA);
        const uint32_t a01 = __shfl(pkx[mt][2 * kk][1], srcA);
        const uint32_t a10 = __shfl(pkx[mt][2 * kk + 1][0], srcA);
        const uint32_t a11 = __shfl(pkx[mt][2 * kk + 1][1], srcA);
        const uint32_t b00 = __shfl(pkx[mt][2 * kk][0], srcB);
        const uint32_t b01 = __shfl(pkx[mt][2 * kk][1], srcB);
        const uint32_t b10 = __shfl(pkx[mt][2 * kk + 1][0], srcB);
        const uint32_t b11 = __shfl(pkx[mt][2 * kk + 1][1], srcB);
        union { uint32_t u[4]; bf16x8 v; } pf;
        pf.u[0] = hi ? a10 : a00;
        pf.u[1] = hi ? a11 : a01;
        pf.u[2] = hi ? b10 : b00;
        pf.u[3] = hi ? b11 : b01;
        #pragma unroll
        for (int dt = 0; dt < 4; ++dt)
          o[mt][dt] = __builtin_amdgcn_mfma_f32_16x16x32_bf16(vf[dt][kk], pf.v, o[mt][dt], 0, 0, 0);
      }
  }

  // epilogue: lsum lanes are col m=l15 -> matches O^T cols; contiguous float4 stores.
  #pragma unroll
  for (int mt = 0; mt < 2; ++mt) {
    lsum[mt] += __shfl_xor(lsum[mt], 16);
    lsum[mt] += __shfl_xor(lsum[mt], 32);
    const float invl = lsum[mt] > 0.f ? 1.0f / lsum[mt] : 0.f;
    const size_t rowbase =
        ((size_t)(b * M_ + m0 + mt * 16 + l15)) * D_ + h * DH_;
    #pragma unroll
    for (int dt = 0; dt < 4; ++dt) {
      float4 st = {o[mt][dt][0] * invl, o[mt][dt][1] * invl,
                   o[mt][dt][2] * invl, o[mt][dt][3] * invl};
      *(float4*)(out + rowbase + dt * 16 + quad * 4) = st;
    }
  }
}

extern "C" void kernel_launch(void* const* d_in, const int* in_sizes, int n_in,
                              void* d_out, int out_size, void* d_ws, size_t ws_size,
                              hipStream_t stream) {
  const float* q = (const float*)d_in[0];
  const float* kv = (const float*)d_in[1];
  const int* kv_mask = (const int*)d_in[2];
  float* out = (float*)d_out;

  // ws layout: kp 16MB | vt 16MB | mb 1KB
  const size_t kp_sz = (size_t)B_ * H_ * N_ * DH_ * sizeof(bf16_t);
  bf16_t* kp = (bf16_t*)d_ws;
  bf16_t* vt = (bf16_t*)((char*)d_ws + kp_sz);
  unsigned long long* mb = (unsigned long long*)((char*)d_ws + 2 * kp_sz);

  prep_k_kernel<<<B_ * N_ / 4, 256, 0, stream>>>(kv, kp);
  prep_v_kernel<<<B_ * 8 * H_, 256, 0, stream>>>(kv, vt);
  prep_mask_kernel<<<B_ * (N_ / 64) / 4, 256, 0, stream>>>(kv_mask, mb);
  attn_kernel<<<(M_ / 128) * 64, 256, 0, stream>>>(q, kp, vt, mb, out);
}